// Round 3
// baseline (890.005 us; speedup 1.0000x reference)
//
#include <hip/hip_runtime.h>
#include <hip/hip_bf16.h>

#define Ss 512
#define Nn 128
#define DIN 256
#define TN 16      // n rows per block
#define NITER 32   // iterations; 2 s per iter -> 64 s per block
#define NSC 8      // s-chunks per (b, ng)

typedef __attribute__((ext_vector_type(8))) __bf16 bf16x8;
typedef __attribute__((ext_vector_type(4))) float f32x4;

__device__ __forceinline__ unsigned short f2bf(float f) {
  unsigned u = __float_as_uint(f);
  u += 0x7fffu + ((u >> 16) & 1u);
  return (unsigned short)(u >> 16);
}
__device__ __forceinline__ float bf2f(unsigned short h) {
  return __uint_as_float(((unsigned)h) << 16);
}

// lgkm-only barrier: does NOT drain vmcnt, so prefetched global loads stay
// in flight across it (the m97 vmcnt(0)-drain is what we're avoiding).
__device__ __forceinline__ void lgkm_barrier() {
  __asm__ __volatile__("s_waitcnt lgkmcnt(0)\ns_barrier" ::: "memory");
}

// ---- prep: split W1 (128x256 fp32) into bf16 hi + lo residual ----
__global__ void prep_w1(const float* __restrict__ W1,
                        unsigned short* __restrict__ w1h,
                        unsigned short* __restrict__ w1l) {
  int i = blockIdx.x * 256 + threadIdx.x;   // grid 128 -> 32768 exact
  float f = W1[i];
  unsigned short h = f2bf(f);
  w1h[i] = h;
  w1l[i] = f2bf(f - bf2f(h));
}

__device__ __forceinline__ void stage_row(unsigned short* xs, int row, int d0,
                                          float4 A, float4 B) {
  unsigned short h0 = f2bf(A.x), h1 = f2bf(A.y), h2 = f2bf(A.z), h3 = f2bf(A.w);
  unsigned short h4 = f2bf(B.x), h5 = f2bf(B.y), h6 = f2bf(B.z), h7 = f2bf(B.w);
  uint4 H;
  H.x = (unsigned)h0 | ((unsigned)h1 << 16);
  H.y = (unsigned)h2 | ((unsigned)h3 << 16);
  H.z = (unsigned)h4 | ((unsigned)h5 << 16);
  H.w = (unsigned)h6 | ((unsigned)h7 << 16);
  unsigned short g0 = f2bf(A.x - bf2f(h0)), g1 = f2bf(A.y - bf2f(h1));
  unsigned short g2 = f2bf(A.z - bf2f(h2)), g3 = f2bf(A.w - bf2f(h3));
  unsigned short g4 = f2bf(B.x - bf2f(h4)), g5 = f2bf(B.y - bf2f(h5));
  unsigned short g6 = f2bf(B.z - bf2f(h6)), g7 = f2bf(B.w - bf2f(h7));
  uint4 L;
  L.x = (unsigned)g0 | ((unsigned)g1 << 16);
  L.y = (unsigned)g2 | ((unsigned)g3 << 16);
  L.z = (unsigned)g4 | ((unsigned)g5 << 16);
  L.w = (unsigned)g6 | ((unsigned)g7 << 16);
  *(uint4*)&xs[row * 520 + d0] = H;
  *(uint4*)&xs[row * 520 + 256 + d0] = L;
}

// ---- fused flash kernel, pipelined: 2 s per iter, 2 lgkm-barriers per iter.
// grid 512 = b(8) x ng(8) x sc(8); block 512 = 8 waves; 64 s per block.
// Unnormalized softmax (reference 0): partials A = sum e*x, l = sum e.
__global__ __launch_bounds__(512, 4) void flash_kernel(
    const float* __restrict__ x, const unsigned short* __restrict__ w1h,
    const unsigned short* __restrict__ w1l, const float* __restrict__ b1,
    const float* __restrict__ wlen, const int* __restrict__ seqlen,
    float* __restrict__ pl, float* __restrict__ pp) {
  __shared__ __align__(16) unsigned short xs[32 * 520];  // rows 0-15: s0, 16-31: s1
  __shared__ float part[8][32];
  const int t = threadIdx.x;
  const int lane = t & 63;
  const int w = t >> 6;
  const int quad = lane >> 4;
  const int l15 = lane & 15;
  const int col = w * 16 + l15;   // hid col 0..127

  const int bi = blockIdx.x;      // b*64 + ng*8 + sc
  const int b = bi >> 6;
  const int ng = (bi >> 3) & 7;
  const int sc = bi & 7;
  const int slen = seqlen[b];
  const int sbase = sc * 64;

  bf16x8 bh[8], bl[8];
#pragma unroll
  for (int ks = 0; ks < 8; ++ks) {
    int off = col * 256 + ks * 32 + quad * 8;
    bh[ks] = *(const bf16x8*)(w1h + off);
    bl[ks] = *(const bf16x8*)(w1l + off);
  }
  const float b1c = b1[col];
  const float wlc = wlen[col];

  const int n_l = t >> 5;        // 0..15 (pool/stage row ownership)
  const int c = t & 31;
  const int d0 = c * 8;          // 8 d-elements per thread

  // float4 pointer to (b, sbase, ng*16+n_l, d0)
  const float4* xr = (const float4*)x +
      (((long)b * Ss + sbase) * Nn + ng * TN + n_l) * 64 + c * 2;
  const long sstr = (long)Nn * 64;  // 8192 float4 per s

  // prologue: tile 0 -> regs -> LDS; prefetch tile 1
  float4 cur0 = xr[0], cur1 = xr[1];
  float4 cur2 = xr[sstr], cur3 = xr[sstr + 1];
  stage_row(xs, n_l, d0, cur0, cur1);
  stage_row(xs, 16 + n_l, d0, cur2, cur3);
  float4 nxt0 = xr[2 * sstr], nxt1 = xr[2 * sstr + 1];
  float4 nxt2 = xr[3 * sstr], nxt3 = xr[3 * sstr + 1];
  lgkm_barrier();

  float acc[8];
#pragma unroll
  for (int j = 0; j < 8; ++j) acc[j] = 0.f;
  float lsum0 = 0.f, lsum1 = 0.f;

  for (int i = 0; i < NITER; ++i) {
    // --- MFMA scores for 32 rows (s0: rows 0-15, s1: rows 16-31) ---
    f32x4 sa0 = {0.f, 0.f, 0.f, 0.f};
    f32x4 sa1 = {0.f, 0.f, 0.f, 0.f};
#pragma unroll
    for (int ks = 0; ks < 8; ++ks) {
      const int k0 = ks * 32 + quad * 8;
      bf16x8 ah0 = *(const bf16x8*)&xs[l15 * 520 + k0];
      bf16x8 al0 = *(const bf16x8*)&xs[l15 * 520 + 256 + k0];
      bf16x8 ah1 = *(const bf16x8*)&xs[(16 + l15) * 520 + k0];
      bf16x8 al1 = *(const bf16x8*)&xs[(16 + l15) * 520 + 256 + k0];
      sa0 = __builtin_amdgcn_mfma_f32_16x16x32_bf16(ah0, bh[ks], sa0, 0, 0, 0);
      sa0 = __builtin_amdgcn_mfma_f32_16x16x32_bf16(al0, bh[ks], sa0, 0, 0, 0);
      sa0 = __builtin_amdgcn_mfma_f32_16x16x32_bf16(ah0, bl[ks], sa0, 0, 0, 0);
      sa1 = __builtin_amdgcn_mfma_f32_16x16x32_bf16(ah1, bh[ks], sa1, 0, 0, 0);
      sa1 = __builtin_amdgcn_mfma_f32_16x16x32_bf16(al1, bh[ks], sa1, 0, 0, 0);
      sa1 = __builtin_amdgcn_mfma_f32_16x16x32_bf16(ah1, bl[ks], sa1, 0, 0, 0);
    }
    // epilogue: relu(+b1)*wlen per col, reduce over 16 cols (l15 dimension)
    float p0 = fmaxf(sa0[0] + b1c, 0.f) * wlc;
    float p1 = fmaxf(sa0[1] + b1c, 0.f) * wlc;
    float p2 = fmaxf(sa0[2] + b1c, 0.f) * wlc;
    float p3 = fmaxf(sa0[3] + b1c, 0.f) * wlc;
    float q0 = fmaxf(sa1[0] + b1c, 0.f) * wlc;
    float q1 = fmaxf(sa1[1] + b1c, 0.f) * wlc;
    float q2 = fmaxf(sa1[2] + b1c, 0.f) * wlc;
    float q3 = fmaxf(sa1[3] + b1c, 0.f) * wlc;
#pragma unroll
    for (int off = 1; off < 16; off <<= 1) {
      p0 += __shfl_xor(p0, off); p1 += __shfl_xor(p1, off);
      p2 += __shfl_xor(p2, off); p3 += __shfl_xor(p3, off);
      q0 += __shfl_xor(q0, off); q1 += __shfl_xor(q1, off);
      q2 += __shfl_xor(q2, off); q3 += __shfl_xor(q3, off);
    }
    if (l15 < 4) {
      float pv = (l15 == 0) ? p0 : (l15 == 1) ? p1 : (l15 == 2) ? p2 : p3;
      float qv = (l15 == 0) ? q0 : (l15 == 1) ? q1 : (l15 == 2) ? q2 : q3;
      part[w][quad * 4 + l15] = pv;
      part[w][16 + quad * 4 + l15] = qv;
    }
    lgkm_barrier();  // part ready; xs MFMA-reads drained

    // --- every lane: e for its two rows (broadcast LDS reads) ---
    float r0 = 0.f, r1 = 0.f;
#pragma unroll
    for (int ww = 0; ww < 8; ++ww) {
      r0 += part[ww][n_l];
      r1 += part[ww][16 + n_l];
    }
    const int s0 = sbase + 2 * i;
    const float m0 = (s0 < slen) ? 1.0f : -10.0f;
    const float m1 = (s0 + 1 < slen) ? 1.0f : -10.0f;
    const float e0 = expf(r0 * m0);
    const float e1 = expf(r1 * m1);
    lsum0 += e0;
    lsum1 += e1;

    // --- pool from fp32 registers (exact) ---
    acc[0] = fmaf(e1, cur2.x, fmaf(e0, cur0.x, acc[0]));
    acc[1] = fmaf(e1, cur2.y, fmaf(e0, cur0.y, acc[1]));
    acc[2] = fmaf(e1, cur2.z, fmaf(e0, cur0.z, acc[2]));
    acc[3] = fmaf(e1, cur2.w, fmaf(e0, cur0.w, acc[3]));
    acc[4] = fmaf(e1, cur3.x, fmaf(e0, cur1.x, acc[4]));
    acc[5] = fmaf(e1, cur3.y, fmaf(e0, cur1.y, acc[5]));
    acc[6] = fmaf(e1, cur3.z, fmaf(e0, cur1.z, acc[6]));
    acc[7] = fmaf(e1, cur3.w, fmaf(e0, cur1.w, acc[7]));

    // --- stage next tile from prefetched regs; rotate; prefetch tile i+2 ---
    if (i + 1 < NITER) {
      stage_row(xs, n_l, d0, nxt0, nxt1);
      stage_row(xs, 16 + n_l, d0, nxt2, nxt3);
      cur0 = nxt0; cur1 = nxt1; cur2 = nxt2; cur3 = nxt3;
      if (i + 2 < NITER) {
        const float4* xp = xr + (long)(2 * i + 4) * sstr;
        nxt0 = xp[0]; nxt1 = xp[1];
        nxt2 = xp[sstr]; nxt3 = xp[sstr + 1];
      }
    }
    lgkm_barrier();  // xs(i+1) staged; part free for rewrite
  }

  // write partials
  {
    float* dst = pp + ((long)bi * TN + n_l) * 256 + d0;
    float4 v0 = {acc[0], acc[1], acc[2], acc[3]};
    float4 v1 = {acc[4], acc[5], acc[6], acc[7]};
    *(float4*)dst = v0;
    *(float4*)(dst + 4) = v1;
  }
  if (c == 0) {
    pl[bi * 32 + n_l] = lsum0;
    pl[bi * 32 + 16 + n_l] = lsum1;
  }
}

// ---- combine partials + gated readout; grid 1024 = (b,n); block 256 ----
__global__ __launch_bounds__(256) void combine_readout(
    const float* __restrict__ pl, const float* __restrict__ pp,
    const float* __restrict__ Wa, const float* __restrict__ ba,
    const float* __restrict__ We, const float* __restrict__ be,
    const float* __restrict__ Wf, const float* __restrict__ bfv,
    float* __restrict__ g) {
  const int bi = blockIdx.x;
  const int b = bi >> 7, n = bi & 127;
  const int ng = n >> 4, nl = n & 15;
  const int t = threadIdx.x;
  __shared__ __align__(16) float p[256];
  __shared__ __align__(16) float tv[256];

  float accd = 0.f, L = 0.f;
#pragma unroll
  for (int sc = 0; sc < NSC; ++sc) {
    const int blk = b * 64 + ng * 8 + sc;
    accd += pp[((long)blk * TN + nl) * 256 + t];
    L += pl[blk * 32 + nl] + pl[blk * 32 + 16 + nl];
  }
  p[t] = accd / L;
  __syncthreads();

  float da = ba[t], de = be[t];
  const float4* pa = (const float4*)p;
  const float4* wa = (const float4*)(Wa + (long)t * 256);
  const float4* we = (const float4*)(We + (long)t * 256);
#pragma unroll 4
  for (int i = 0; i < 64; ++i) {
    float4 pv = pa[i], av = wa[i], ev = we[i];
    da += pv.x * av.x + pv.y * av.y + pv.z * av.z + pv.w * av.w;
    de += pv.x * ev.x + pv.y * ev.y + pv.z * ev.z + pv.w * ev.w;
  }
  float sig = 1.0f / (1.0f + expf(-da));
  float th = tanhf(de);
  tv[t] = sig * th;
  __syncthreads();
  if (t < 64) {
    float go = bfv[t];
    const float4* wf = (const float4*)(Wf + (long)t * 256);
    const float4* tp = (const float4*)tv;
#pragma unroll 4
    for (int i = 0; i < 64; ++i) {
      float4 a = tp[i], q = wf[i];
      go += a.x * q.x + a.y * q.y + a.z * q.z + a.w * q.w;
    }
    g[(long)bi * 64 + t] = go;
  }
}

// ---- finalize: out[b,:] = sum_n g / 128 + max_n g ----
__global__ __launch_bounds__(512) void finalize_kernel(const float* __restrict__ g,
                                                       float* __restrict__ out) {
  const int b = blockIdx.x;   // 8
  const int t = threadIdx.x;  // 512
  const int o = t & 63, ns = t >> 6;
  float sum = 0.f, mx = -INFINITY;
  for (int n = ns; n < Nn; n += 8) {
    float v = g[((long)b * Nn + n) * 64 + o];
    sum += v;
    mx = fmaxf(mx, v);
  }
  __shared__ float s1[8][64], s2[8][64];
  s1[ns][o] = sum;
  s2[ns][o] = mx;
  __syncthreads();
  if (ns == 0) {
#pragma unroll
    for (int ww = 1; ww < 8; ++ww) {
      sum += s1[ww][o];
      mx = fmaxf(mx, s2[ww][o]);
    }
    out[b * 64 + o] = sum * (1.0f / 128.0f) + mx;
  }
}

extern "C" void kernel_launch(void* const* d_in, const int* in_sizes, int n_in,
                              void* d_out, int out_size, void* d_ws, size_t ws_size,
                              hipStream_t stream) {
  const float* x   = (const float*)d_in[0];
  const int* seql  = (const int*)d_in[1];
  const float* W1  = (const float*)d_in[2];
  const float* b1  = (const float*)d_in[3];
  const float* wl  = (const float*)d_in[4];
  const float* Wa  = (const float*)d_in[5];
  const float* ba  = (const float*)d_in[6];
  const float* We  = (const float*)d_in[7];
  const float* be  = (const float*)d_in[8];
  const float* Wf  = (const float*)d_in[9];
  const float* bfv = (const float*)d_in[10];
  float* out = (float*)d_out;

  char* ws = (char*)d_ws;
  unsigned short* w1h = (unsigned short*)(ws);                 // 64 KB
  unsigned short* w1l = (unsigned short*)(ws + 65536);         // 64 KB
  float* pl = (float*)(ws + 131072);                           // 64 KB (512*32)
  float* pp = (float*)(ws + 131072 + 65536);                   // 8 MB (512*16*256)
  float* g  = (float*)(ws + 131072 + 65536 + 8388608);         // 256 KB

  prep_w1<<<128, 256, 0, stream>>>(W1, w1h, w1l);
  flash_kernel<<<512, 512, 0, stream>>>(x, w1h, w1l, b1, wl, seql, pl, pp);
  combine_readout<<<1024, 256, 0, stream>>>(pl, pp, Wa, ba, We, be, Wf, bfv, g);
  finalize_kernel<<<8, 512, 0, stream>>>(g, out);
}

// Round 4
// 859.971 us; speedup vs baseline: 1.0349x; 1.0349x over previous
//
#include <hip/hip_runtime.h>
#include <hip/hip_bf16.h>

#define Ss 512
#define Nn 128
#define DIN 256
#define TN 16      // n rows per block
#define NITER 32   // iterations; 2 s per iter -> 64 s per block
#define NSC 8      // s-chunks per (b, ng)

typedef __attribute__((ext_vector_type(8))) __bf16 bf16x8;
typedef __attribute__((ext_vector_type(4))) float f32x4;

__device__ __forceinline__ unsigned short f2bf(float f) {
  unsigned u = __float_as_uint(f);
  u += 0x7fffu + ((u >> 16) & 1u);
  return (unsigned short)(u >> 16);
}
__device__ __forceinline__ float bf2f(unsigned short h) {
  return __uint_as_float(((unsigned)h) << 16);
}

// lgkm-only barrier: does NOT drain vmcnt, so prefetched global loads stay
// in flight across it.
__device__ __forceinline__ void lgkm_barrier() {
  __asm__ __volatile__("s_waitcnt lgkmcnt(0)\ns_barrier" ::: "memory");
}

// ---- prep: split W1 (128x256 fp32) into bf16 hi + lo residual ----
__global__ void prep_w1(const float* __restrict__ W1,
                        unsigned short* __restrict__ w1h,
                        unsigned short* __restrict__ w1l) {
  int i = blockIdx.x * 256 + threadIdx.x;   // grid 128 -> 32768 exact
  float f = W1[i];
  unsigned short h = f2bf(f);
  w1h[i] = h;
  w1l[i] = f2bf(f - bf2f(h));
}

__device__ __forceinline__ void stage_row(unsigned short* xs, int row, int d0,
                                          float4 A, float4 B) {
  unsigned short h0 = f2bf(A.x), h1 = f2bf(A.y), h2 = f2bf(A.z), h3 = f2bf(A.w);
  unsigned short h4 = f2bf(B.x), h5 = f2bf(B.y), h6 = f2bf(B.z), h7 = f2bf(B.w);
  uint4 H;
  H.x = (unsigned)h0 | ((unsigned)h1 << 16);
  H.y = (unsigned)h2 | ((unsigned)h3 << 16);
  H.z = (unsigned)h4 | ((unsigned)h5 << 16);
  H.w = (unsigned)h6 | ((unsigned)h7 << 16);
  unsigned short g0 = f2bf(A.x - bf2f(h0)), g1 = f2bf(A.y - bf2f(h1));
  unsigned short g2 = f2bf(A.z - bf2f(h2)), g3 = f2bf(A.w - bf2f(h3));
  unsigned short g4 = f2bf(B.x - bf2f(h4)), g5 = f2bf(B.y - bf2f(h5));
  unsigned short g6 = f2bf(B.z - bf2f(h6)), g7 = f2bf(B.w - bf2f(h7));
  uint4 L;
  L.x = (unsigned)g0 | ((unsigned)g1 << 16);
  L.y = (unsigned)g2 | ((unsigned)g3 << 16);
  L.z = (unsigned)g4 | ((unsigned)g5 << 16);
  L.w = (unsigned)g6 | ((unsigned)g7 << 16);
  *(uint4*)&xs[row * 520 + d0] = H;
  *(uint4*)&xs[row * 520 + 256 + d0] = L;
}

// ---- fused flash kernel, pipelined: 2 s per iter, 2 lgkm-barriers per iter.
// grid 512 = b(8) x ng(8) x sc(8); block 512 = 8 waves; 64 s per block.
// Unnormalized softmax: partials pp = sum e*x, pl = sum e.
// Pooling reads LDS (hi+lo, 2^-17 exact) at the SAME addresses this thread
// staged -> same-thread ordering, no extra barrier; cur regs eliminated to
// keep VGPR < 128 (round-3 regression root cause).
__global__ __launch_bounds__(512, 4) void flash_kernel(
    const float* __restrict__ x, const unsigned short* __restrict__ w1h,
    const unsigned short* __restrict__ w1l, const float* __restrict__ b1,
    const float* __restrict__ wlen, const int* __restrict__ seqlen,
    float* __restrict__ pl, float* __restrict__ pp) {
  __shared__ __align__(16) unsigned short xs[32 * 520];  // rows 0-15: s0, 16-31: s1
  __shared__ float part[8][32];
  const int t = threadIdx.x;
  const int lane = t & 63;
  const int w = t >> 6;
  const int quad = lane >> 4;
  const int l15 = lane & 15;
  const int col = w * 16 + l15;   // hid col 0..127

  const int bi = blockIdx.x;      // b*64 + ng*8 + sc
  const int b = bi >> 6;
  const int ng = (bi >> 3) & 7;
  const int sc = bi & 7;
  const int slen = seqlen[b];
  const int sbase = sc * 64;

  bf16x8 bh[8], bl[8];
#pragma unroll
  for (int ks = 0; ks < 8; ++ks) {
    int off = col * 256 + ks * 32 + quad * 8;
    bh[ks] = *(const bf16x8*)(w1h + off);
    bl[ks] = *(const bf16x8*)(w1l + off);
  }
  const float b1c = b1[col];
  const float wlc = wlen[col];

  const int n_l = t >> 5;        // 0..15 (stage/pool row ownership)
  const int c = t & 31;
  const int d0 = c * 8;          // 8 d-elements per thread

  // float4 pointer to (b, sbase, ng*16+n_l, d0)
  const float4* xr = (const float4*)x +
      (((long)b * Ss + sbase) * Nn + ng * TN + n_l) * 64 + c * 2;
  const long sstr = (long)Nn * 64;  // 8192 float4 per s

  // prologue: issue all 8 loads, stage tile 0 (regs die), keep tile 1 in nxt
  {
    float4 a0 = xr[0], a1 = xr[1];
    float4 a2 = xr[sstr], a3 = xr[sstr + 1];
    stage_row(xs, n_l, d0, a0, a1);
    stage_row(xs, 16 + n_l, d0, a2, a3);
  }
  float4 nxt0 = xr[2 * sstr], nxt1 = xr[2 * sstr + 1];
  float4 nxt2 = xr[3 * sstr], nxt3 = xr[3 * sstr + 1];
  lgkm_barrier();

  float acc[8];
#pragma unroll
  for (int j = 0; j < 8; ++j) acc[j] = 0.f;
  float lsum0 = 0.f, lsum1 = 0.f;

  for (int i = 0; i < NITER; ++i) {
    // --- phase A: MFMA scores for 32 rows (s0: rows 0-15, s1: rows 16-31) ---
    f32x4 sa0 = {0.f, 0.f, 0.f, 0.f};
    f32x4 sa1 = {0.f, 0.f, 0.f, 0.f};
#pragma unroll
    for (int ks = 0; ks < 8; ++ks) {
      const int k0 = ks * 32 + quad * 8;
      bf16x8 ah0 = *(const bf16x8*)&xs[l15 * 520 + k0];
      bf16x8 al0 = *(const bf16x8*)&xs[l15 * 520 + 256 + k0];
      bf16x8 ah1 = *(const bf16x8*)&xs[(16 + l15) * 520 + k0];
      bf16x8 al1 = *(const bf16x8*)&xs[(16 + l15) * 520 + 256 + k0];
      sa0 = __builtin_amdgcn_mfma_f32_16x16x32_bf16(ah0, bh[ks], sa0, 0, 0, 0);
      sa0 = __builtin_amdgcn_mfma_f32_16x16x32_bf16(al0, bh[ks], sa0, 0, 0, 0);
      sa0 = __builtin_amdgcn_mfma_f32_16x16x32_bf16(ah0, bl[ks], sa0, 0, 0, 0);
      sa1 = __builtin_amdgcn_mfma_f32_16x16x32_bf16(ah1, bh[ks], sa1, 0, 0, 0);
      sa1 = __builtin_amdgcn_mfma_f32_16x16x32_bf16(al1, bh[ks], sa1, 0, 0, 0);
      sa1 = __builtin_amdgcn_mfma_f32_16x16x32_bf16(ah1, bl[ks], sa1, 0, 0, 0);
    }
    float p0 = fmaxf(sa0[0] + b1c, 0.f) * wlc;
    float p1 = fmaxf(sa0[1] + b1c, 0.f) * wlc;
    float p2 = fmaxf(sa0[2] + b1c, 0.f) * wlc;
    float p3 = fmaxf(sa0[3] + b1c, 0.f) * wlc;
    float q0 = fmaxf(sa1[0] + b1c, 0.f) * wlc;
    float q1 = fmaxf(sa1[1] + b1c, 0.f) * wlc;
    float q2 = fmaxf(sa1[2] + b1c, 0.f) * wlc;
    float q3 = fmaxf(sa1[3] + b1c, 0.f) * wlc;
#pragma unroll
    for (int off = 1; off < 16; off <<= 1) {
      p0 += __shfl_xor(p0, off); p1 += __shfl_xor(p1, off);
      p2 += __shfl_xor(p2, off); p3 += __shfl_xor(p3, off);
      q0 += __shfl_xor(q0, off); q1 += __shfl_xor(q1, off);
      q2 += __shfl_xor(q2, off); q3 += __shfl_xor(q3, off);
    }
    if (l15 < 4) {
      float pv = (l15 == 0) ? p0 : (l15 == 1) ? p1 : (l15 == 2) ? p2 : p3;
      float qv = (l15 == 0) ? q0 : (l15 == 1) ? q1 : (l15 == 2) ? q2 : q3;
      part[w][quad * 4 + l15] = pv;
      part[w][16 + quad * 4 + l15] = qv;
    }
    lgkm_barrier();  // part visible; all MFMA xs reads drained

    // --- phase B: e per row (broadcast part reads); pool from own LDS slots ---
    float r0 = 0.f, r1 = 0.f;
#pragma unroll
    for (int ww = 0; ww < 8; ++ww) {
      r0 += part[ww][n_l];
      r1 += part[ww][16 + n_l];
    }
    const int s0 = sbase + 2 * i;
    const float m0 = (s0 < slen) ? 1.0f : -10.0f;
    const float m1 = (s0 + 1 < slen) ? 1.0f : -10.0f;
    const float e0 = expf(r0 * m0);
    const float e1 = expf(r1 * m1);
    lsum0 += e0;
    lsum1 += e1;
    {
      bf16x8 xh0 = *(const bf16x8*)&xs[n_l * 520 + d0];
      bf16x8 xl0 = *(const bf16x8*)&xs[n_l * 520 + 256 + d0];
      bf16x8 xh1 = *(const bf16x8*)&xs[(16 + n_l) * 520 + d0];
      bf16x8 xl1 = *(const bf16x8*)&xs[(16 + n_l) * 520 + 256 + d0];
#pragma unroll
      for (int j = 0; j < 8; ++j) {
        float v0 = (float)xh0[j] + (float)xl0[j];
        float v1 = (float)xh1[j] + (float)xl1[j];
        acc[j] = fmaf(e1, v1, fmaf(e0, v0, acc[j]));
      }
    }

    // --- phase C: stage next tile (same-thread WAR on own slots); prefetch ---
    if (i + 1 < NITER) {
      stage_row(xs, n_l, d0, nxt0, nxt1);
      stage_row(xs, 16 + n_l, d0, nxt2, nxt3);
      if (i + 2 < NITER) {
        const float4* xp = xr + (long)(2 * i + 4) * sstr;
        nxt0 = xp[0]; nxt1 = xp[1];
        nxt2 = xp[sstr]; nxt3 = xp[sstr + 1];
      }
    }
    lgkm_barrier();  // xs(i+1) staged; part free for rewrite
  }

  // write partials
  {
    float* dst = pp + ((long)bi * TN + n_l) * 256 + d0;
    float4 v0 = {acc[0], acc[1], acc[2], acc[3]};
    float4 v1 = {acc[4], acc[5], acc[6], acc[7]};
    *(float4*)dst = v0;
    *(float4*)(dst + 4) = v1;
  }
  if (c == 0) {
    pl[bi * 32 + n_l] = lsum0;
    pl[bi * 32 + 16 + n_l] = lsum1;
  }
}

// ---- combine partials + gated readout; grid 1024 = (b,n); block 256 ----
__global__ __launch_bounds__(256) void combine_readout(
    const float* __restrict__ pl, const float* __restrict__ pp,
    const float* __restrict__ Wa, const float* __restrict__ ba,
    const float* __restrict__ We, const float* __restrict__ be,
    const float* __restrict__ Wf, const float* __restrict__ bfv,
    float* __restrict__ g) {
  const int bi = blockIdx.x;
  const int b = bi >> 7, n = bi & 127;
  const int ng = n >> 4, nl = n & 15;
  const int t = threadIdx.x;
  __shared__ __align__(16) float p[256];
  __shared__ __align__(16) float tv[256];

  float accd = 0.f, L = 0.f;
#pragma unroll
  for (int sc = 0; sc < NSC; ++sc) {
    const int blk = b * 64 + ng * 8 + sc;
    accd += pp[((long)blk * TN + nl) * 256 + t];
    L += pl[blk * 32 + nl] + pl[blk * 32 + 16 + nl];
  }
  p[t] = accd / L;
  __syncthreads();

  float da = ba[t], de = be[t];
  const float4* pa = (const float4*)p;
  const float4* wa = (const float4*)(Wa + (long)t * 256);
  const float4* we = (const float4*)(We + (long)t * 256);
#pragma unroll 4
  for (int i = 0; i < 64; ++i) {
    float4 pv = pa[i], av = wa[i], ev = we[i];
    da += pv.x * av.x + pv.y * av.y + pv.z * av.z + pv.w * av.w;
    de += pv.x * ev.x + pv.y * ev.y + pv.z * ev.z + pv.w * ev.w;
  }
  float sig = 1.0f / (1.0f + expf(-da));
  float th = tanhf(de);
  tv[t] = sig * th;
  __syncthreads();
  if (t < 64) {
    float go = bfv[t];
    const float4* wf = (const float4*)(Wf + (long)t * 256);
    const float4* tp = (const float4*)tv;
#pragma unroll 4
    for (int i = 0; i < 64; ++i) {
      float4 a = tp[i], q = wf[i];
      go += a.x * q.x + a.y * q.y + a.z * q.z + a.w * q.w;
    }
    g[(long)bi * 64 + t] = go;
  }
}

// ---- finalize: out[b,:] = sum_n g / 128 + max_n g ----
__global__ __launch_bounds__(512) void finalize_kernel(const float* __restrict__ g,
                                                       float* __restrict__ out) {
  const int b = blockIdx.x;   // 8
  const int t = threadIdx.x;  // 512
  const int o = t & 63, ns = t >> 6;
  float sum = 0.f, mx = -INFINITY;
  for (int n = ns; n < Nn; n += 8) {
    float v = g[((long)b * Nn + n) * 64 + o];
    sum += v;
    mx = fmaxf(mx, v);
  }
  __shared__ float s1[8][64], s2[8][64];
  s1[ns][o] = sum;
  s2[ns][o] = mx;
  __syncthreads();
  if (ns == 0) {
#pragma unroll
    for (int ww = 1; ww < 8; ++ww) {
      sum += s1[ww][o];
      mx = fmaxf(mx, s2[ww][o]);
    }
    out[b * 64 + o] = sum * (1.0f / 128.0f) + mx;
  }
}

extern "C" void kernel_launch(void* const* d_in, const int* in_sizes, int n_in,
                              void* d_out, int out_size, void* d_ws, size_t ws_size,
                              hipStream_t stream) {
  const float* x   = (const float*)d_in[0];
  const int* seql  = (const int*)d_in[1];
  const float* W1  = (const float*)d_in[2];
  const float* b1  = (const float*)d_in[3];
  const float* wl  = (const float*)d_in[4];
  const float* Wa  = (const float*)d_in[5];
  const float* ba  = (const float*)d_in[6];
  const float* We  = (const float*)d_in[7];
  const float* be  = (const float*)d_in[8];
  const float* Wf  = (const float*)d_in[9];
  const float* bfv = (const float*)d_in[10];
  float* out = (float*)d_out;

  char* ws = (char*)d_ws;
  unsigned short* w1h = (unsigned short*)(ws);                 // 64 KB
  unsigned short* w1l = (unsigned short*)(ws + 65536);         // 64 KB
  float* pl = (float*)(ws + 131072);                           // 64 KB (512*32)
  float* pp = (float*)(ws + 131072 + 65536);                   // 8 MB (512*16*256)
  float* g  = (float*)(ws + 131072 + 65536 + 8388608);         // 256 KB

  prep_w1<<<128, 256, 0, stream>>>(W1, w1h, w1l);
  flash_kernel<<<512, 512, 0, stream>>>(x, w1h, w1l, b1, wl, seql, pl, pp);
  combine_readout<<<1024, 256, 0, stream>>>(pl, pp, Wa, ba, We, be, Wf, bfv, g);
  finalize_kernel<<<8, 512, 0, stream>>>(g, out);
}